// Round 3
// baseline (162.061 us; speedup 1.0000x reference)
//
#include <hip/hip_runtime.h>

// out[b,co,h,w] = sum_ci dq( conv3x3(x[b,ci], W[ci,co]) + b[ci,co] )
//   dq(y) = rint(y * s) / s,  s = (float)(15/9)  — bit-exact f32 emulation of
//   the XLA-CPU float32 reference: conv = seq fma over (kh,kw) from 0, bias
//   added after, f32 mul / rint(half-even) / true f32 divide, sum over ci as
//   plain sequential f32 adds. No compiler contraction outside explicit fmaf.

constexpr int B_    = 8;
constexpr int CIN   = 16;
constexpr int COUT  = 32;
constexpr int H_    = 112;
constexpr int W_    = 112;
constexpr int TILE  = 16;           // 112 = 7 * 16, exact tiling
constexpr int HALO  = TILE + 2;     // 18
constexpr int LDSW  = HALO + 2;     // pad row stride to 20 words

__global__ __launch_bounds__(256, 2)
void conv_quant_sum_kernel(const float* __restrict__ x,
                           const float* __restrict__ w,
                           const float* __restrict__ bias,
                           float* __restrict__ out)
{
#pragma clang fp contract(off)
    const float QS = (float)(15.0 / 9.0);   // 1.66666663f, matches jax weak-typed f32 scale

    __shared__ float xs[CIN][HALO][LDSW];

    const int tx = threadIdx.x & 15;
    const int ty = threadIdx.x >> 4;
    const int tile_x = blockIdx.x * TILE;
    const int tile_y = blockIdx.y * TILE;
    const int b = blockIdx.z;

    // ---- stage x halo tile (18x18 per channel, zero-padded at borders) ----
    const float* xb = x + (size_t)b * CIN * H_ * W_;
    for (int idx = threadIdx.x; idx < CIN * HALO * HALO; idx += 256) {
        int ci  = idx / (HALO * HALO);
        int rem = idx - ci * (HALO * HALO);
        int r   = rem / HALO;
        int c   = rem - r * HALO;
        int gh  = tile_y + r - 1;
        int gw  = tile_x + c - 1;
        float v = 0.0f;
        if ((unsigned)gh < (unsigned)H_ && (unsigned)gw < (unsigned)W_)
            v = xb[ci * H_ * W_ + gh * W_ + gw];
        xs[ci][r][c] = v;
    }
    __syncthreads();

    float acc[COUT];
#pragma unroll
    for (int co = 0; co < COUT; ++co) acc[co] = 0.0f;

    for (int ci = 0; ci < CIN; ++ci) {
        float xv[9];
#pragma unroll
        for (int kh = 0; kh < 3; ++kh)
#pragma unroll
            for (int kw = 0; kw < 3; ++kw)
                xv[kh * 3 + kw] = xs[ci][ty + kh][tx + kw];

        // wave-uniform weight/bias indices -> scalar loads, zero VALU cost
        const float* wc = w + ci * COUT * 9;
        const float* bc = bias + ci * COUT;
#pragma unroll
        for (int co = 0; co < COUT; ++co) {
            // conv: sequential fma over (kh,kw), seeded from 0 (bias NOT folded)
            float s = 0.0f;
#pragma unroll
            for (int k = 0; k < 9; ++k)
                s = fmaf(xv[k], wc[co * 9 + k], s);
            float y = s + bc[co];        // separate f32 add (reference: y + b)
            float t = y * QS;            // f32 mul by f32 scale
            float q = rintf(t);          // v_rndne_f32: round half to even
            float dq = q / QS;           // TRUE f32 divide (correctly rounded)
            acc[co] = acc[co] + dq;      // plain sequential add over ci
        }
    }

    float* ob = out + (size_t)b * COUT * H_ * W_;
    const int oh = tile_y + ty;
    const int ow = tile_x + tx;
#pragma unroll
    for (int co = 0; co < COUT; ++co)
        ob[co * H_ * W_ + oh * W_ + ow] = acc[co];
}

extern "C" void kernel_launch(void* const* d_in, const int* in_sizes, int n_in,
                              void* d_out, int out_size, void* d_ws, size_t ws_size,
                              hipStream_t stream)
{
    const float* x    = (const float*)d_in[0];
    const float* w    = (const float*)d_in[1];
    const float* bias = (const float*)d_in[2];
    float* out        = (float*)d_out;

    dim3 grid(W_ / TILE, H_ / TILE, B_);   // (7, 7, 8)
    dim3 block(256);
    conv_quant_sum_kernel<<<grid, block, 0, stream>>>(x, w, bias, out);
}

// Round 4
// 97.643 us; speedup vs baseline: 1.6597x; 1.6597x over previous
//
#include <hip/hip_runtime.h>

// out[b,co,h,w] = sum_ci dq( conv3x3(x[b,ci], W[ci,co]) + b[ci,co] )
// Bit-exactness contract (verified R3, absmax==0): conv = sequential fmaf over
// (kh,kw) seeded from 0; bias added after as plain f32 add; t = y * (float)(15/9);
// rintf (half-even). Dequant divide replaced by fmaf(q, 0.6f, acc): it sits
// AFTER the round so error is <=2 ulp/term (~3e-5 total vs 0.43 threshold).

constexpr int B_    = 8;
constexpr int CIN   = 16;
constexpr int COUT  = 32;
constexpr int H_    = 112;
constexpr int W_    = 112;
constexpr int TILE  = 16;           // 112 = 7 * 16, exact tiling
constexpr int HALO  = TILE + 2;     // 18
constexpr int LDSW  = HALO + 2;     // pad row stride to 20 words
constexpr int COG   = 8;            // co per block (4 groups -> grid x4)

__global__ __launch_bounds__(256, 6)   // 6 blocks/CU (LDS-capped: 6*23KB=138KB)
void conv_quant_sum_kernel(const float* __restrict__ x,
                           const float* __restrict__ w,
                           const float* __restrict__ bias,
                           float* __restrict__ out)
{
#pragma clang fp contract(off)
    const float QS  = (float)(15.0 / 9.0);  // 1.66666663f
    const float DQI = 0.6f;                 // dequant multiplier (post-round, ulp-safe)

    __shared__ float xs[CIN][HALO][LDSW];

    const int tx = threadIdx.x & 15;
    const int ty = threadIdx.x >> 4;
    const int tile_x = blockIdx.x * TILE;
    const int tile_y = blockIdx.y * TILE;
    const int b   = blockIdx.z >> 2;        // batch
    const int cog = (blockIdx.z & 3) * COG; // co group base

    // ---- stage x halo tile (18x18 per channel, zero-padded at borders) ----
    const float* xb = x + (size_t)b * CIN * H_ * W_;
    for (int idx = threadIdx.x; idx < CIN * HALO * HALO; idx += 256) {
        int ci  = idx / (HALO * HALO);
        int rem = idx - ci * (HALO * HALO);
        int r   = rem / HALO;
        int c   = rem - r * HALO;
        int gh  = tile_y + r - 1;
        int gw  = tile_x + c - 1;
        float v = 0.0f;
        if ((unsigned)gh < (unsigned)H_ && (unsigned)gw < (unsigned)W_)
            v = xb[ci * H_ * W_ + gh * W_ + gw];
        xs[ci][r][c] = v;
    }
    __syncthreads();

    float acc[COG];
#pragma unroll
    for (int co = 0; co < COG; ++co) acc[co] = 0.0f;

    for (int ci = 0; ci < CIN; ++ci) {
        float xv[9];
#pragma unroll
        for (int kh = 0; kh < 3; ++kh)
#pragma unroll
            for (int kw = 0; kw < 3; ++kw)
                xv[kh * 3 + kw] = xs[ci][ty + kh][tx + kw];

        // wave-uniform weight/bias indices -> scalar loads, zero VALU cost
        const float* wc = w + (ci * COUT + cog) * 9;
        const float* bc = bias + ci * COUT + cog;
#pragma unroll
        for (int co = 0; co < COG; ++co) {
            float s = 0.0f;                       // conv seeded from 0
#pragma unroll
            for (int k = 0; k < 9; ++k)
                s = fmaf(xv[k], wc[co * 9 + k], s);
            float y = s + bc[co];                 // bias: separate f32 add
            float q = rintf(y * QS);              // v_rndne_f32, half-even
            acc[co] = fmaf(q, DQI, acc[co]);      // dequant+sum (post-round)
        }
    }

    float* ob = out + ((size_t)b * COUT + cog) * H_ * W_;
    const int oh = tile_y + ty;
    const int ow = tile_x + tx;
#pragma unroll
    for (int co = 0; co < COG; ++co)
        ob[co * H_ * W_ + oh * W_ + ow] = acc[co];
}

extern "C" void kernel_launch(void* const* d_in, const int* in_sizes, int n_in,
                              void* d_out, int out_size, void* d_ws, size_t ws_size,
                              hipStream_t stream)
{
    const float* x    = (const float*)d_in[0];
    const float* w    = (const float*)d_in[1];
    const float* bias = (const float*)d_in[2];
    float* out        = (float*)d_out;

    dim3 grid(W_ / TILE, H_ / TILE, B_ * 4);   // (7, 7, 32) = 1568 blocks
    dim3 block(256);
    conv_quant_sum_kernel<<<grid, block, 0, stream>>>(x, w, bias, out);
}